// Round 3
// baseline (1760.247 us; speedup 1.0000x reference)
//
#include <hip/hip_runtime.h>

// p4->p4 group-equivariant conv, reduced form:
//   out[b,m,i,ho,wo] = sum_{c,kh,kw} rot_i(x)[b, c, ((m>>4)+i)&3, ho+kh, wo+kw] * W2[m,c,kh,kw]
//   W2[m,c,k] = sum_{j=0..3} w[4m+j, c, k]   (inner group-sum folded into weights: 4x fewer MACs)
// rot_i = clockwise rotation i quarter-turns:
//   i=0: (h,w)->(h,w)   i=1: ->(H-1-w, h)   i=2: ->(H-1-h, W-1-w)   i=3: ->(w, W-1-h)

#define TH 16
#define TW 16
#define CH 16   // channel chunk staged in LDS

__global__ void prep_w_kernel(const float* __restrict__ w, float* __restrict__ W2) {
  // W2 layout [c][k][m] : idx = (c*9 + k)*64 + m   (m contiguous for float4 reads)
  int idx = blockIdx.x * 256 + threadIdx.x;
  if (idx >= 64 * 9 * 64) return;
  int m = idx & 63;
  int k = (idx >> 6) % 9;
  int c = idx / (64 * 9);
  float s = 0.f;
#pragma unroll
  for (int j = 0; j < 4; ++j)
    s += w[(size_t)((4 * m + j) * 64 + c) * 9 + k];
  W2[idx] = s;
}

__global__ __launch_bounds__(256) void conv_p4_kernel(
    const float* __restrict__ x, const float* __restrict__ wraw,
    const float* __restrict__ W2, int use_w2, float* __restrict__ out) {
  // grid: (8 tiles_w, 8 tiles_h, b*16 + mg*4 + i)
  const int tilew = blockIdx.x, tileh = blockIdx.y;
  const int z = blockIdx.z;
  const int b = z >> 4;
  const int mg = (z >> 2) & 3;   // m>>4 group of output channels (16 m per block)
  const int i = z & 3;           // rotation index
  const int gp = (mg + i) & 3;   // input group slice after roll
  const int ho0 = tileh * TH, wo0 = tilew * TW;

  __shared__ float xs[CH][18][20];  // stored PRE-ROTATED; row stride 20 keeps float4 align
  __shared__ float ws[CH][9][16];   // W2 slice [c][k][m_local]

  const int tid = threadIdx.x;
  const int tm = tid >> 6;   // 0..3 : m sub-block (4 m each)
  const int p = tid & 63;
  const int pw = p & 3;      // wo group of 4
  const int ph = p >> 2;     // 0..15 : ho within tile

  float acc[4][4] = {};  // [m][wo]

  // original-frame origin of the 18x18 input footprint (may be negative at edges; unused cells)
  int h0, w0;
  if (i == 0)      { h0 = ho0;            w0 = wo0; }
  else if (i == 1) { h0 = 128 - 18 - wo0; w0 = ho0; }
  else if (i == 2) { h0 = 128 - 18 - ho0; w0 = 128 - 18 - wo0; }
  else             { h0 = wo0;            w0 = 128 - 18 - ho0; }

  const float* xb = x + ((size_t)(b * 64) * 4 + gp) * (128 * 128);  // c stride = 4*16384

  for (int c0 = 0; c0 < 64; c0 += CH) {
    // ---- stage weights: 16c * 9k * 16m = 2304 floats ----
    for (int t = tid; t < CH * 9 * 16; t += 256) {
      int mm = t & 15;
      int kk = (t >> 4) % 9;
      int cc = t / (16 * 9);
      float v;
      if (use_w2) {
        v = W2[((c0 + cc) * 9 + kk) * 64 + mg * 16 + mm];
      } else {
        v = 0.f;
        int m = mg * 16 + mm;
#pragma unroll
        for (int j = 0; j < 4; ++j)
          v += wraw[(size_t)((4 * m + j) * 64 + (c0 + cc)) * 9 + kk];
      }
      ws[cc][kk][mm] = v;
    }
    // ---- stage x: read original-frame rect coalesced, write rotated into LDS ----
    for (int t = tid; t < CH * 18 * 18; t += 256) {
      int col = t % 18;
      int r = (t / 18) % 18;
      int cc = t / (18 * 18);
      int hh = h0 + r, ww = w0 + col;
      float v = 0.f;
      if ((unsigned)hh < 128u && (unsigned)ww < 128u)
        v = xb[(size_t)(c0 + cc) * 4 * 16384 + hh * 128 + ww];
      int a, bb;  // rotated-frame in-tile coords
      if (i == 0)      { a = r;        bb = col; }
      else if (i == 1) { a = col;      bb = 17 - r; }
      else if (i == 2) { a = 17 - r;   bb = 17 - col; }
      else             { a = 17 - col; bb = r; }
      xs[cc][a][bb] = v;
    }
    __syncthreads();

    for (int c = 0; c < CH; ++c) {
      // 3 rows x 6 cols window for this thread's 4 output pixels
      float xv[3][6];
#pragma unroll
      for (int r = 0; r < 3; ++r) {
        const float* rowp = &xs[c][ph + r][pw * 4];
        float4 v4 = *(const float4*)rowp;   // 16B-aligned (stride 20 floats)
        xv[r][0] = v4.x; xv[r][1] = v4.y; xv[r][2] = v4.z; xv[r][3] = v4.w;
        xv[r][4] = rowp[4]; xv[r][5] = rowp[5];
      }
#pragma unroll
      for (int kh = 0; kh < 3; ++kh)
#pragma unroll
        for (int kw = 0; kw < 3; ++kw) {
          float4 w4 = *(const float4*)&ws[c][kh * 3 + kw][tm * 4];
#pragma unroll
          for (int q = 0; q < 4; ++q) {
            float xvq = xv[kh][q + kw];
            acc[0][q] += xvq * w4.x;
            acc[1][q] += xvq * w4.y;
            acc[2][q] += xvq * w4.z;
            acc[3][q] += xvq * w4.w;
          }
        }
    }
    __syncthreads();
  }

  // ---- write out[b][m][i][ho][wo] ----
  const int ho = ho0 + ph;
  if (ho < 126) {
#pragma unroll
    for (int mi = 0; mi < 4; ++mi) {
      int m = mg * 16 + tm * 4 + mi;
      size_t base = ((((size_t)b * 64 + m) * 4 + i) * 126 + ho) * 126;
#pragma unroll
      for (int q = 0; q < 4; ++q) {
        int wo = wo0 + pw * 4 + q;
        if (wo < 126) out[base + wo] = acc[mi][q];
      }
    }
  }
}

extern "C" void kernel_launch(void* const* d_in, const int* in_sizes, int n_in,
                              void* d_out, int out_size, void* d_ws, size_t ws_size,
                              hipStream_t stream) {
  const float* x = (const float*)d_in[0];
  const float* w = (const float*)d_in[1];
  float* out = (float*)d_out;

  const size_t w2_bytes = (size_t)64 * 9 * 64 * sizeof(float);
  int use_w2 = (ws_size >= w2_bytes) ? 1 : 0;
  float* W2 = (float*)d_ws;

  if (use_w2) {
    prep_w_kernel<<<dim3(144), dim3(256), 0, stream>>>(w, W2);
  }
  dim3 grid(8, 8, 16 * 16);  // tiles_w, tiles_h, b*16 + mg*4 + i
  conv_p4_kernel<<<grid, dim3(256), 0, stream>>>(x, w, W2, use_w2, out);
}